// Round 8
// baseline (229.170 us; speedup 1.0000x reference)
//
#include <hip/hip_runtime.h>
#include <cfloat>
#include <climits>
#include <stdint.h>

#define NTRAIN 50000
#define DIM 64
#define BQ 128
#define NCLS 10
#define KSEL 16
#define QPB 32                 // queries per block (scan)
#define QG (BQ / QPB)          // 4 query groups
#define THREADS 512            // 8 waves
#define TROWS 512              // rows staged per tile (64 per wave)
#define TPAD 68                // float4 rows; 8-lane phases conflict-free (R1/R2/R6/R7: 0 conflicts)
#define NSAMP 1024             // sample rows for tau
#define SSTRIPES 64            // cand stripes: 128*64*16*8 = 1 MB (R7-proven ws fit)
#define CAP 1920               // LDS candidate buffer entries (mean ~390, +59 sigma)

// packed candidate: [d:32][q:5][row:16]  (row < 50000 < 2^16)
// For a FIXED q, u64 '<' == lex (d, row) — exact tie-break by lowest row.
__device__ __forceinline__ uint64_t pack_dqr(float d, int q, int r) {
    return ((uint64_t)__float_as_uint(d) << 32) | ((uint64_t)(uint32_t)q << 16) | (uint32_t)r;
}

// sorted-ascending top-16 insert (exact, order-invariant); 16-elem arrays promote
__device__ __forceinline__ void ins16(uint64_t (&K)[KSEL], uint64_t pk) {
    if (pk < K[KSEL - 1]) {
        K[KSEL - 1] = pk;
#pragma unroll
        for (int j = KSEL - 1; j > 0; --j)
            if (K[j] < K[j - 1]) { uint64_t t = K[j]; K[j] = K[j - 1]; K[j - 1] = t; }
    }
}

__device__ __forceinline__ uint64_t adv16(const uint64_t (&K)[KSEL], int c) {
    uint64_t nh = ~0ULL;
#pragma unroll
    for (int q = 1; q < KSEL; ++q)
        if (c == q) nh = K[q];
    return nh;
}

// K1: tau[q] = exact 16th smallest distance over rows 0..NSAMP-1.
// Distance chain bit-identical to knn_scan (adds only -> no reassociation).
__global__ __launch_bounds__(64) void knn_tau(
    const float* __restrict__ train, const float* __restrict__ xtest,
    float* __restrict__ tau)
{
    const int q = blockIdx.x, lane = threadIdx.x;

    float4 qv[DIM / 4];
    {
        const float* qp = xtest + (size_t)q * DIM;
#pragma unroll
        for (int c = 0; c < DIM / 4; ++c) qv[c] = *(const float4*)(qp + 4 * c);
    }

    uint64_t K[KSEL];
#pragma unroll
    for (int j = 0; j < KSEL; ++j) K[j] = ~0ULL;

    for (int t = 0; t < NSAMP / 64; ++t) {
        const int r = lane + 64 * t;
        const float* rp = train + (size_t)r * DIM;
        float acc = 0.0f;
#pragma unroll
        for (int c = 0; c < DIM / 4; ++c) {
            const float4 tv = *(const float4*)(rp + 4 * c);
            const float s01 = fabsf(tv.x - qv[c].x) + fabsf(tv.y - qv[c].y);
            const float s23 = fabsf(tv.z - qv[c].z) + fabsf(tv.w - qv[c].w);
            acc += s01 + s23;
        }
        ins16(K, (((uint64_t)__float_as_uint(acc)) << 32) | (uint32_t)r);
    }

    // full-wave 64-list cursor merge; last winner = 16th smallest
    uint64_t h = K[0]; int c = 0; uint64_t last = ~0ULL;
#pragma unroll
    for (int r = 0; r < KSEL; ++r) {
        uint64_t m = h, o;
#pragma unroll
        for (int sh = 1; sh < 64; sh <<= 1) {
            o = __shfl_xor((unsigned long long)m, sh);
            if (o < m) m = o;
        }
        if (m == h) { ++c; h = adv16(K, c); }
        last = m;
    }
    if (lane == 0) tau[q] = __uint_as_float((uint32_t)(last >> 32));
}

// K2: full scan. Hot loop = distance engine + 1 cmp/cell; passing cells
// (~1.6%) append to an LDS buffer (set-deterministic). No k-lists in loop.
__global__ __launch_bounds__(THREADS, 1) void knn_scan(
    const float* __restrict__ train, const float* __restrict__ xtest,
    const float* __restrict__ tau, uint64_t* __restrict__ cand, int stripe_len)
{
    __shared__ float qs[QPB * TPAD];                        // 8.7 KB
    __shared__ __align__(16) float ts[TROWS * TPAD];        // 139.3 KB
    __shared__ uint64_t bufc[CAP];                          // 15.4 KB
    __shared__ int lcnt;

    const int bx     = blockIdx.x;
    const int stripe = bx % SSTRIPES;
    const int qgrp   = bx / SSTRIPES;
    const int q0     = qgrp * QPB;
    const int tid    = threadIdx.x;
    const int w      = tid >> 6;
    const int lane   = tid & 63;
    const int qg     = lane >> 3;      // 0..7 query sub-index
    const int rg     = lane & 7;       // 0..7 row sub-index

    const int r0 = stripe * stripe_len;
    const int r1 = min(NTRAIN, r0 + stripe_len);

    if (tid == 0) lcnt = 0;
    for (int f = tid; f < QPB * (DIM / 4); f += THREADS) {
        const int ql = f >> 4, c = f & 15;
        *(float4*)&qs[ql * TPAD + 4 * c] =
            *(const float4*)&xtest[(size_t)(q0 + ql) * DIM + 4 * c];
    }

    float tauv[4];
#pragma unroll
    for (int i = 0; i < 4; ++i) tauv[i] = tau[q0 + qg + 8 * i];

    for (int base = r0; base < r1; base += TROWS) {
        const int nr = min(TROWS, r1 - base);
        __syncthreads();                         // prev readers done; qs/lcnt visible (1st iter)
        for (int f = tid; f < nr * (DIM / 4); f += THREADS) {
            const int r = f >> 4, c = f & 15;
            *(float4*)&ts[r * TPAD + 4 * c] =
                *(const float4*)&train[(size_t)(base + r) * DIM + 4 * c];
        }
        __syncthreads();                         // tile ready

        // wave tile: 32q x 64r; lane tile: 4q (qg+8i) x 8r (w*64+rg+8j)
        float acc[4][8];
#pragma unroll
        for (int i = 0; i < 4; ++i)
#pragma unroll
            for (int j = 0; j < 8; ++j) acc[i][j] = 0.0f;

#pragma unroll 4
        for (int c = 0; c < DIM / 4; ++c) {
            float4 qv[4], tv[8];
#pragma unroll
            for (int i = 0; i < 4; ++i)
                qv[i] = *(const float4*)&qs[(qg + 8 * i) * TPAD + 4 * c];
#pragma unroll
            for (int j = 0; j < 8; ++j)
                tv[j] = *(const float4*)&ts[(w * 64 + rg + 8 * j) * TPAD + 4 * c];
#pragma unroll
            for (int i = 0; i < 4; ++i)
#pragma unroll
                for (int j = 0; j < 8; ++j) {
                    const float s01 = fabsf(tv[j].x - qv[i].x) + fabsf(tv[j].y - qv[i].y);
                    const float s23 = fabsf(tv[j].z - qv[i].z) + fabsf(tv[j].w - qv[i].w);
                    acc[i][j] += s01 + s23;
                }
        }

        // gate & append: every true top-16 row satisfies d <= tau (= sample 16th)
        const int rb = base + w * 64 + rg;
#pragma unroll
        for (int j = 0; j < 8; ++j) {
            const int r = rb + 8 * j;
            if (r < r1) {
#pragma unroll
                for (int i = 0; i < 4; ++i) {
                    if (acc[i][j] <= tauv[i]) {
                        const int p = atomicAdd(&lcnt, 1);
                        if (p < CAP) bufc[p] = pack_dqr(acc[i][j], qg + 8 * i, r);
                    }
                }
            }
        }
    }

    __syncthreads();                             // all appends visible
    const int m = min(lcnt, CAP);
    if (tid < QPB) {                             // thread t owns query q0+t
        uint64_t kk[KSEL];
#pragma unroll
        for (int j = 0; j < KSEL; ++j) kk[j] = ~0ULL;
        for (int e = 0; e < m; ++e) {
            const uint64_t v = bufc[e];          // broadcast read (same addr all threads)
            if ((int)((v >> 16) & 31) == tid) ins16(kk, v);
        }
#pragma unroll
        for (int j = 0; j < KSEL; ++j)
            cand[((size_t)(q0 + tid) * SSTRIPES + stripe) * KSEL + j] = kk[j];
    }
}

// K3: exact top-16 over 64*16 candidate slots, one-hot vote, argmax
__global__ __launch_bounds__(64) void knn_final(
    const uint64_t* __restrict__ cand, const float* __restrict__ ttarget,
    int* __restrict__ out, int ncand)
{
    const int b = blockIdx.x, lane = threadIdx.x;

    uint64_t k[KSEL];
#pragma unroll
    for (int j = 0; j < KSEL; ++j) k[j] = ~0ULL;
    for (int c = lane; c < ncand; c += 64)
        ins16(k, cand[(size_t)b * ncand + c]);

    uint64_t h = k[0]; int c = 0;
    float v = 0.0f;
#pragma unroll
    for (int r = 0; r < KSEL; ++r) {
        uint64_t m = h, o;
#pragma unroll
        for (int sh = 1; sh < 64; sh <<= 1) {
            o = __shfl_xor((unsigned long long)m, sh);
            if (o < m) m = o;
        }
        if (m == h) { ++c; h = adv16(k, c); }
        const int wi = (int)(m & 0xFFFFu);       // row field; winners always real (>=16 real cands)
        if (lane < NCLS) v += ttarget[(size_t)wi * NCLS + lane];
    }

    float bv = (lane < NCLS) ? v : -1.0f;
    int   bc = lane;
#pragma unroll
    for (int sh = 1; sh < 64; sh <<= 1) {
        const float xv = __shfl_xor(bv, sh);
        const int   xc = __shfl_xor(bc, sh);
        if (xv > bv || (xv == bv && xc < bc)) { bv = xv; bc = xc; }  // tie -> lowest class
    }
    if (lane == 0) out[b] = bc;
}

extern "C" void kernel_launch(void* const* d_in, const int* in_sizes, int n_in,
                              void* d_out, int out_size, void* d_ws, size_t ws_size,
                              hipStream_t stream) {
    const float* train   = (const float*)d_in[0];
    const float* ttarget = (const float*)d_in[1];
    const float* xtest   = (const float*)d_in[2];
    int* out = (int*)d_out;

    const int stripe_len = (NTRAIN + SSTRIPES - 1) / SSTRIPES;   // 782

    float*    tau  = (float*)d_ws;                                // 512 B
    uint64_t* cand = (uint64_t*)((char*)d_ws + 512);              // 1 MB

    hipLaunchKernelGGL(knn_tau, dim3(BQ), dim3(64), 0, stream, train, xtest, tau);
    hipLaunchKernelGGL(knn_scan, dim3(QG * SSTRIPES), dim3(THREADS), 0, stream,
                       train, xtest, tau, cand, stripe_len);
    hipLaunchKernelGGL(knn_final, dim3(BQ), dim3(64), 0, stream,
                       cand, ttarget, out, SSTRIPES * KSEL);
}